// Round 2
// baseline (557.980 us; speedup 1.0000x reference)
//
#include <hip/hip_runtime.h>
#include <stdint.h>

// Problem constants (B=2, Nr=40962, in_ch=128, out_ch=64). FP32 I/O.
#define NR     40962
#define NH     163842      // 4*NR-6
#define NR7    286734      // NR*7
#define M_UP   40962
#define M_CV   327684      // B*NH
#define BN_EPS 1e-5f
#define SLOPE  0.2f

typedef __attribute__((ext_vector_type(8))) short  short8;
typedef __attribute__((ext_vector_type(4))) float  f32x4;
typedef unsigned short ushort_t;

__device__ __forceinline__ ushort_t f2bf(float f) {
  union { float f; uint32_t u; } v; v.f = f;
  uint32_t r = v.u + 0x7fffu + ((v.u >> 16) & 1u);  // RNE
  return (ushort_t)(r >> 16);
}
__device__ __forceinline__ float bf2f(ushort_t h) {
  union { uint32_t u; float f; } v; v.u = ((uint32_t)h) << 16;
  return v.f;
}
__device__ __forceinline__ int clampi(int v, int hi) {
  v = v < 0 ? 0 : v;
  return v >= hi ? hi - 1 : v;
}

// ---------------------------------------------------------------------------
// Barrier-free gather-GEMM. 256x64 tile, 4 waves, 64 rows/wave.
// A-fragments load GLOBAL->VGPR directly (16B per lane, the exact MFMA
// fragment) with register double-buffering — no As LDS, no barriers in the
// K-loop, per-wave vmcnt pipelining by the compiler.
// B (64 x KHALF bf16) staged to LDS once per stage (NSTAGE=2 for K=896),
// [n][k] layout, 16B-slot XOR swizzle (slot^(n&7)). 3 barriers total.
// MODE 0: dense A bf16 [M][128], K=128, out bf16 stride NW=448 (up-GEMM).
// MODE 1: conv1 gather, A row = xcat[idx][128 elems], K=896, out bf16.
// MODE 2: conv2 gather, A row = y1[idx][64 elems],   K=448, out fp32.
// FSTATS: fused per-channel sum/sumsq -> statsPart[16 slices][128].
// ---------------------------------------------------------------------------
template<int MODE, int KHALF, int NSTAGE, int NCH, bool FSTATS>
__global__ __launch_bounds__(256, 2) void gemm_conv(
    const ushort_t* __restrict__ Asrc,
    const int*      __restrict__ neigh,
    const float*    __restrict__ Wf,     // fp32 [K][NW]
    const float*    __restrict__ bias,
    void*           __restrict__ OutV,
    float*          __restrict__ statsPart,
    int M, int NW)
{
  __shared__ __align__(16) ushort_t Bs[64 * KHALF];

  const int tid  = threadIdx.x;
  const int wv   = tid >> 6;
  const int lane = tid & 63;
  const int r16  = lane & 15;
  const int q    = lane >> 4;
  const int mTile = blockIdx.y * 256;
  const int nTile = blockIdx.x * 64;
  constexpr int ROWE = (MODE == 2) ? 64 : 128;   // A row length (elems)

  // Gather row indices: 4 row-groups x 7 neighbor slots, per-lane registers.
  int idx[4][7];
  if constexpr (MODE != 0) {
#pragma unroll
    for (int rg = 0; rg < 4; ++rg) {
      int r = mTile + wv * 64 + rg * 16 + r16;
      if (r >= M) r = M - 1;
      const int gb = (r >= NH) ? 1 : 0;
      const int gn = r - gb * NH;
#pragma unroll
      for (int j = 0; j < 7; ++j)
        idx[rg][j] = gb * NH + clampi(neigh[gn * 7 + j], NH);
    }
  }

  f32x4 acc[4][4];
#pragma unroll
  for (int a = 0; a < 4; ++a)
#pragma unroll
    for (int i = 0; i < 4; ++i) acc[a][i] = (f32x4){0.f, 0.f, 0.f, 0.f};

  short8 areg[2][4][2];   // [buf][rowgroup][ks] — statically indexed (unrolled)

  auto loadA = [&](int buf, int ch) {
    if constexpr (MODE == 0) {
#pragma unroll
      for (int rg = 0; rg < 4; ++rg) {
        int r = mTile + wv * 64 + rg * 16 + r16;
        if (r >= M) r = M - 1;
        const ushort_t* base = Asrc + (size_t)r * 128 + ch * 64 + q * 8;
        areg[buf][rg][0] = *(const short8*)(base);
        areg[buf][rg][1] = *(const short8*)(base + 32);
      }
    } else {
      const int j  = (MODE == 1) ? (ch >> 1) : ch;
      const int cb = (MODE == 1) ? ((ch & 1) << 6) : 0;
#pragma unroll
      for (int rg = 0; rg < 4; ++rg) {
        const ushort_t* base = Asrc + (size_t)idx[rg][j] * ROWE + cb + q * 8;
        areg[buf][rg][0] = *(const short8*)(base);
        areg[buf][rg][1] = *(const short8*)(base + 32);
      }
    }
  };

  // Stage B half: W fp32 [K][NW] -> Bs[n][KHALF] bf16, XOR-swizzled 16B slots.
  // Thread t: n = t&63, k-segment = (t>>6)*16. Loads are full coalesced rows.
  auto stageB = [&](int s) {
    const int n = tid & 63, kseg = tid >> 6;
#pragma unroll
    for (int i = 0; i < KHALF / 64; ++i) {
      const int kloc = i * 64 + kseg * 16;
      float f[16];
#pragma unroll
      for (int u = 0; u < 16; ++u)
        f[u] = Wf[(size_t)(s * KHALF + kloc + u) * NW + nTile + n];
      const int slot0 = kloc >> 3;
#pragma unroll
      for (int hh = 0; hh < 2; ++hh) {
        short8 v;
#pragma unroll
        for (int u = 0; u < 8; ++u) v[u] = (short)f2bf(f[hh * 8 + u]);
        const int sl = slot0 + hh;
        const int sp = (sl & ~7) | ((sl ^ n) & 7);
        *(short8*)&Bs[n * KHALF + sp * 8] = v;
      }
    }
  };

  auto compute = [&](int buf, int chLoc) {
#pragma unroll
    for (int ks = 0; ks < 2; ++ks) {
#pragma unroll
      for (int ct = 0; ct < 4; ++ct) {
        const int sl = chLoc * 8 + ks * 4 + q;
        const int n  = ct * 16 + r16;
        const int sp = (sl & ~7) | ((sl ^ n) & 7);
        const short8 b = *(const short8*)&Bs[n * KHALF + sp * 8];
#pragma unroll
        for (int rg = 0; rg < 4; ++rg)
          acc[rg][ct] = __builtin_amdgcn_mfma_f32_16x16x32_bf16(
              areg[buf][rg][ks], b, acc[rg][ct], 0, 0, 0);
      }
    }
  };

  loadA(0, 0);            // issued before staging: latency hides under stageB
  stageB(0);
  __syncthreads();

#pragma unroll
  for (int s = 0; s < NSTAGE; ++s) {
    if (s > 0) {
      __syncthreads();    // all waves done reading previous Bs
      stageB(s);
      __syncthreads();
    }
    const int chBase = s * (KHALF / 64);
#pragma unroll
    for (int c2 = 0; c2 < KHALF / 64; ++c2) {
      const int ch = chBase + c2;
      if (ch + 1 < NCH) loadA((ch + 1) & 1, ch + 1);
      compute(ch & 1, c2);
    }
  }

  // epilogue: C/D layout col=lane&15, row=(lane>>4)*4+reg
  float s1a[4] = {0.f, 0.f, 0.f, 0.f};
  float s2a[4] = {0.f, 0.f, 0.f, 0.f};
#pragma unroll
  for (int ct = 0; ct < 4; ++ct) {
    const int colg = nTile + ct * 16 + r16;
    const float bv = bias[colg];
#pragma unroll
    for (int rg = 0; rg < 4; ++rg) {
#pragma unroll
      for (int i = 0; i < 4; ++i) {
        const int rowg = mTile + wv * 64 + rg * 16 + q * 4 + i;
        const float y = acc[rg][ct][i] + bv;
        if (rowg < M) {
          if constexpr (MODE == 2)
            ((float*)OutV)[(size_t)rowg * NW + colg] = y;
          else
            ((ushort_t*)OutV)[(size_t)rowg * NW + colg] = f2bf(y);
          if constexpr (FSTATS) { s1a[ct] += y; s2a[ct] += y * y; }
        }
      }
    }
  }

  if constexpr (FSTATS) {
    __syncthreads();                     // all Bs reads done; reuse as scratch
    float* Sred  = (float*)&Bs[0];       // [4 waves][64 ch]
    float* S2red = Sred + 256;
#pragma unroll
    for (int ct = 0; ct < 4; ++ct) {
      float v = s1a[ct], w = s2a[ct];
      v += __shfl_xor(v, 16, 64); v += __shfl_xor(v, 32, 64);
      w += __shfl_xor(w, 16, 64); w += __shfl_xor(w, 32, 64);
      if (q == 0) {
        Sred[wv * 64 + ct * 16 + r16]  = v;
        S2red[wv * 64 + ct * 16 + r16] = w;
      }
    }
    __syncthreads();
    if (tid < 64) {
      float v = Sred[tid] + Sred[64 + tid] + Sred[128 + tid] + Sred[192 + tid];
      float w = S2red[tid] + S2red[64 + tid] + S2red[128 + tid] + S2red[192 + tid];
      float* p = statsPart + (size_t)(blockIdx.y & 15) * 128;
      atomicAdd(&p[tid], v);
      atomicAdd(&p[64 + tid], w);
    }
  }
}

// ---------------------------------------------------------------------------
// xup build: pick/mean from h ((NR,448) bf16 viewed as (NR7,64)), writing the
// LOW 64 channels of xcat rows (row stride 128).
// ---------------------------------------------------------------------------
__global__ __launch_bounds__(256) void build_xup_kernel(
    const ushort_t* __restrict__ h, const int* __restrict__ top,
    const int* __restrict__ down, ushort_t* __restrict__ xcatB, long long total)
{
  const long long gid = (long long)blockIdx.x * 256 + threadIdx.x;
  if (gid >= total) return;
  const int n  = (int)(gid >> 3);
  const int c0 = (int)(gid & 7) * 8;
  short8 v;
  if (n < NR) {
    const int idx = clampi(top[n], NR7);
    v = *(const short8*)(h + (size_t)idx * 64 + c0);
  } else {
    const int d  = n - NR;
    const int i0 = clampi(down[d * 2], NR7);
    const int i1 = clampi(down[d * 2 + 1], NR7);
    short8 u0 = *(const short8*)(h + (size_t)i0 * 64 + c0);
    short8 u1 = *(const short8*)(h + (size_t)i1 * 64 + c0);
#pragma unroll
    for (int i = 0; i < 8; ++i)
      v[i] = (short)f2bf(0.5f * (bf2f((ushort_t)u0[i]) + bf2f((ushort_t)u1[i])));
  }
  *(short8*)(xcatB + (size_t)n * 128 + c0) = v;
}

// x2 fp32 -> bf16 into HIGH 64 channels of xcat (row stride 128)
__global__ __launch_bounds__(256) void cvt_x2_kernel(
    const float* __restrict__ x2, ushort_t* __restrict__ xcat, long long n8)
{
  const long long gid = (long long)blockIdx.x * 256 + threadIdx.x;
  if (gid >= n8) return;
  const long long n = gid >> 3;
  const int c0 = (int)(gid & 7) * 8;
  const f32x4 f0 = *(const f32x4*)(x2 + n * 64 + c0);
  const f32x4 f1 = *(const f32x4*)(x2 + n * 64 + c0 + 4);
  short8 v;
#pragma unroll
  for (int i = 0; i < 4; ++i) {
    v[i]     = (short)f2bf(f0[i]);
    v[i + 4] = (short)f2bf(f1[i]);
  }
  *(short8*)(xcat + n * 128 + 64 + c0) = v;
}

// x1 fp32 -> bf16 dense [40962][128]
__global__ __launch_bounds__(256) void cvt_bf_kernel(
    const float* __restrict__ src, ushort_t* __restrict__ dst, long long n8)
{
  const long long gid = (long long)blockIdx.x * 256 + threadIdx.x;
  if (gid >= n8) return;
  const f32x4 f0 = *(const f32x4*)(src + gid * 8);
  const f32x4 f1 = *(const f32x4*)(src + gid * 8 + 4);
  short8 v;
#pragma unroll
  for (int i = 0; i < 4; ++i) {
    v[i]     = (short)f2bf(f0[i]);
    v[i + 4] = (short)f2bf(f1[i]);
  }
  *(short8*)(dst + gid * 8) = v;
}

__global__ __launch_bounds__(256) void zero_kernel(float* __restrict__ p, int n) {
  const int gid = blockIdx.x * 256 + threadIdx.x;
  if (gid < n) p[gid] = 0.f;
}

// Fallback stats over fp32 buffer -> 16 partial slices
__global__ __launch_bounds__(256) void stats_f32_kernel(
    const float* __restrict__ buf, float* __restrict__ part, int rows)
{
  const int tid = threadIdx.x;
  const int c   = tid & 63;
  const int rl  = tid >> 6;
  float s = 0.f, s2 = 0.f;
  for (int r = blockIdx.x * 4 + rl; r < rows; r += gridDim.x * 4) {
    const float v = buf[(size_t)r * 64 + c];
    s += v; s2 += v * v;
  }
  __shared__ float sh[2][256];
  sh[0][tid] = s; sh[1][tid] = s2;
  __syncthreads();
  if (tid < 64) {
#pragma unroll
    for (int i = 1; i < 4; ++i) { s += sh[0][tid + 64 * i]; s2 += sh[1][tid + 64 * i]; }
    float* p = part + (size_t)(blockIdx.x & 15) * 128;
    atomicAdd(&p[c], s);
    atomicAdd(&p[64 + c], s2);
  }
}

// Fallback stats over bf16 buffer -> 16 partial slices
__global__ __launch_bounds__(256) void stats_bf16_kernel(
    const ushort_t* __restrict__ buf, float* __restrict__ part, int rows)
{
  const int tid = threadIdx.x;
  const int c   = tid & 63;
  const int rl  = tid >> 6;
  float s = 0.f, s2 = 0.f;
  for (int r = blockIdx.x * 4 + rl; r < rows; r += gridDim.x * 4) {
    const float v = bf2f(buf[(size_t)r * 64 + c]);
    s += v; s2 += v * v;
  }
  __shared__ float sh[2][256];
  sh[0][tid] = s; sh[1][tid] = s2;
  __syncthreads();
  if (tid < 64) {
#pragma unroll
    for (int i = 1; i < 4; ++i) { s += sh[0][tid + 64 * i]; s2 += sh[1][tid + 64 * i]; }
    float* p = part + (size_t)(blockIdx.x & 15) * 128;
    atomicAdd(&p[c], s);
    atomicAdd(&p[64 + c], s2);
  }
}

// Reduce 16 partial slices -> final [sc[64] | sh[64]] at part+2048
__global__ void finalize_kernel(float* __restrict__ part,
                                const float* __restrict__ gamma,
                                const float* __restrict__ beta)
{
  const int c = threadIdx.x;  // 64
  float s = 0.f, s2 = 0.f;
  for (int i = 0; i < 16; ++i) { s += part[i * 128 + c]; s2 += part[i * 128 + 64 + c]; }
  const float invN = 1.0f / (float)M_CV;
  const float mean = s * invN;
  float var = fmaxf(s2 * invN - mean * mean, 0.f);
  const float sc = gamma[c] * rsqrtf(var + BN_EPS);
  float* fin = part + 2048;
  fin[c] = sc;
  fin[64 + c] = beta[c] - mean * sc;
}

// In-place y = lrelu(v*sc[c] + sh[c]); fin = [sc[64] | sh[64]]
template<bool F32>
__global__ __launch_bounds__(256) void bnl_kernel(
    void* __restrict__ bufV, const float* __restrict__ fin, long long nvec)
{
  const long long gid = (long long)blockIdx.x * 256 + threadIdx.x;
  if (gid >= nvec) return;
  if constexpr (F32) {
    float* buf = (float*)bufV;
    const int c0 = (int)((gid * 4) & 63);
    f32x4 v = *(f32x4*)(buf + gid * 4);
#pragma unroll
    for (int i = 0; i < 4; ++i) {
      const float y = v[i] * fin[c0 + i] + fin[64 + c0 + i];
      v[i] = (y >= 0.f) ? y : SLOPE * y;
    }
    *(f32x4*)(buf + gid * 4) = v;
  } else {
    ushort_t* buf = (ushort_t*)bufV;
    const int c0 = (int)((gid * 8) & 63);
    short8 v = *(short8*)(buf + gid * 8);
#pragma unroll
    for (int i = 0; i < 8; ++i) {
      float y = bf2f((ushort_t)v[i]) * fin[c0 + i] + fin[64 + c0 + i];
      y = (y >= 0.f) ? y : SLOPE * y;
      v[i] = (short)f2bf(y);
    }
    *(short8*)(buf + gid * 8) = v;
  }
}

// ---------------------------------------------------------------------------
extern "C" void kernel_launch(void* const* d_in, const int* in_sizes, int n_in,
                              void* d_out, int out_size, void* d_ws, size_t ws_size,
                              hipStream_t stream)
{
  const float* x1   = (const float*)d_in[0];
  const float* x2   = (const float*)d_in[1];
  const int*   neigh= (const int*)d_in[2];
  const int*   top  = (const int*)d_in[3];
  const int*   down = (const int*)d_in[4];
  const float* upW  = (const float*)d_in[5];
  const float* upb  = (const float*)d_in[6];
  const float* c1W  = (const float*)d_in[7];
  const float* c1b  = (const float*)d_in[8];
  const float* g1   = (const float*)d_in[9];
  const float* b1   = (const float*)d_in[10];
  const float* c2W  = (const float*)d_in[11];
  const float* c2b  = (const float*)d_in[12];
  const float* g2   = (const float*)d_in[13];
  const float* b2   = (const float*)d_in[14];

  // d_out (83,887,104 B) staging plan:
  //   [0, 83886080)  xcat bf16 [B*NH][128]: cols 0:64 = xup, 64:128 = bf16(x2)
  //   x1bf (10,486,272 B) overlays the start of batch-b's xcat region; dead
  //   before build_xup/cvt_x2 write there (strictly sequential stream).
  //   xcat dead after conv1 -> out fp32 reuses d_out.
  // ws: y1 bf16 [B*NH][64] = 41,943,552 (h bf16 36.7MB overlays it in phase 1).
  //   Gated tail (+17,408 B): st1 (8,704) + st2 (8,704).
  // Weights are read fp32 directly from d_in inside the GEMMs (during conv1
  // the live set xcat+y1 leaves only ~91KB slack -> no room for Wt).
  char* dob = (char*)d_out;
  ushort_t* xcat = (ushort_t*)dob;
  float*    outb = (float*)d_out;
  ushort_t* hbuf = (ushort_t*)d_ws;
  ushort_t* ybuf = (ushort_t*)d_ws;

  const bool gated = ws_size >= (size_t)(41943552 + 17408);
  float* st1 = gated ? (float*)((char*)d_ws + 41943552) : (float*)d_out;
  float* st2 = gated ? (float*)((char*)d_ws + 41943552 + 8704) : (float*)d_ws;

  if (gated) zero_kernel<<<17, 256, 0, stream>>>(st1, 4352);  // st1+st2 adjacent

  // Phase 1 — per batch: x1->bf16 (overlay); h = x1bf @ upW + upb; xup->xcat
  for (int b = 0; b < 2; ++b) {
    ushort_t* x1bf = xcat + (size_t)b * NH * 128;
    cvt_bf_kernel<<<2561, 256, 0, stream>>>(x1 + (size_t)b * M_UP * 128,
                                            x1bf, 655392LL);
    gemm_conv<0, 128, 1, 2, false><<<dim3(7, 161), 256, 0, stream>>>(
        x1bf, nullptr, upW, upb, hbuf, nullptr, M_UP, 448);
    build_xup_kernel<<<5121, 256, 0, stream>>>(
        hbuf, top, down, xcat + (size_t)b * NH * 128, (long long)NH * 8);
  }
  // x2 -> bf16 high channels (after both up-GEMMs: overwrites x1bf overlays)
  cvt_x2_kernel<<<10241, 256, 0, stream>>>(x2, xcat, 2621472LL);

  // Phase 2 — y1 = meshconv1(xcat) -> ws (+ fused BN1 stats if gated)
  if (gated) {
    gemm_conv<1, 448, 2, 14, true><<<dim3(1, 1281), 256, 0, stream>>>(
        xcat, neigh, c1W, c1b, ybuf, st1, M_CV, 64);
  } else {
    gemm_conv<1, 448, 2, 14, false><<<dim3(1, 1281), 256, 0, stream>>>(
        xcat, neigh, c1W, c1b, ybuf, nullptr, M_CV, 64);
    zero_kernel<<<9, 256, 0, stream>>>(st1, 2176);     // xcat dead now
    stats_bf16_kernel<<<2048, 256, 0, stream>>>(ybuf, st1, M_CV);
  }
  finalize_kernel<<<1, 64, 0, stream>>>(st1, g1, b1);
  bnl_kernel<false><<<10241, 256, 0, stream>>>(ybuf, st1 + 2048, 2621472LL);

  // Phase 3 — out = meshconv2(y1) -> d_out fp32 (+ fused BN2 stats if gated)
  if (gated) {
    gemm_conv<2, 448, 1, 7, true><<<dim3(1, 1281), 256, 0, stream>>>(
        ybuf, neigh, c2W, c2b, outb, st2, M_CV, 64);
  } else {
    gemm_conv<2, 448, 1, 7, false><<<dim3(1, 1281), 256, 0, stream>>>(
        ybuf, neigh, c2W, c2b, outb, nullptr, M_CV, 64);
    zero_kernel<<<9, 256, 0, stream>>>(st2, 2176);     // y1 dead now
    stats_f32_kernel<<<2048, 256, 0, stream>>>(outb, st2, M_CV);
  }
  finalize_kernel<<<1, 64, 0, stream>>>(st2, g2, b2);
  bnl_kernel<true><<<20481, 256, 0, stream>>>(outb, st2 + 2048, 5242944LL);
}

// Round 3
// 540.411 us; speedup vs baseline: 1.0325x; 1.0325x over previous
//
#include <hip/hip_runtime.h>
#include <stdint.h>

// Problem constants (B=2, Nr=40962, in_ch=128, out_ch=64). FP32 I/O.
#define NR     40962
#define NH     163842      // 4*NR-6
#define NR7    286734      // NR*7
#define M_UP   40962
#define M_CV   327684      // B*NH
#define BN_EPS 1e-5f
#define SLOPE  0.2f

typedef __attribute__((ext_vector_type(8))) short  short8;
typedef __attribute__((ext_vector_type(4))) short  s16x4;
typedef __attribute__((ext_vector_type(4))) float  f32x4;
typedef unsigned short ushort_t;

__device__ __forceinline__ ushort_t f2bf(float f) {
  union { float f; uint32_t u; } v; v.f = f;
  uint32_t r = v.u + 0x7fffu + ((v.u >> 16) & 1u);  // RNE
  return (ushort_t)(r >> 16);
}
__device__ __forceinline__ float bf2f(ushort_t h) {
  union { uint32_t u; float f; } v; v.u = ((uint32_t)h) << 16;
  return v.f;
}
__device__ __forceinline__ int clampi(int v, int hi) {
  v = v < 0 ? 0 : v;
  return v >= hi ? hi - 1 : v;
}

// Barrier that waits only LDS ops — A-gathers (vmcnt) stay in flight across it.
__device__ __forceinline__ void lds_barrier() {
  asm volatile("s_waitcnt lgkmcnt(0)" ::: "memory");
  __builtin_amdgcn_s_barrier();
  __builtin_amdgcn_sched_barrier(0);
}

// ---------------------------------------------------------------------------
// Gather-GEMM, 128x64 tile, 4 waves x 32 rows. K chunked by 64.
// A: global->VGPR fragments (16B/lane, the exact MFMA fragment), 2-chunk-ahead
//    register prefetch (areg[3]) — rides through barriers (never drained).
// B: per-chunk LDS double buffer (2 x 64x64 bf16 = 16 KB), staged from fp32 W
//    each chunk; one lgkmcnt-only barrier per chunk (no vmcnt drain).
//    16B-slot XOR swizzle (slot ^ n) on both write and read.
// MODE 0: dense A bf16 [M][128], K=128 (up-GEMM), out bf16 stride NW.
// MODE 1: conv1 gather, k->(j=ch>>1, half=ch&1), row=xcat[idx][128], out bf16.
// MODE 2: conv2 gather, j=ch, row=y1[idx][64], out fp32.
// FSTATS: fused per-channel sum/sumsq -> statsPart[16 slices][128].
// Occupancy target: VGPR<=128 (4 waves/SIMD) x 4 blocks/CU (LDS 16KB).
// ---------------------------------------------------------------------------
template<int MODE, int NCH, bool FSTATS>
__global__ __launch_bounds__(256, 4) void gemm_conv(
    const ushort_t* __restrict__ Asrc,
    const int*      __restrict__ neigh,
    const float*    __restrict__ Wf,     // fp32 [K][NW]
    const float*    __restrict__ bias,
    void*           __restrict__ OutV,
    float*          __restrict__ statsPart,
    int M, int NW)
{
  __shared__ __align__(16) ushort_t Bs[2][64 * 64];

  const int tid  = threadIdx.x;
  const int wv   = tid >> 6;
  const int lane = tid & 63;
  const int r16  = lane & 15;
  const int q    = lane >> 4;
  const int mTile = blockIdx.y * 128;
  const int nTile = blockIdx.x * 64;
  constexpr int ROWE = (MODE == 2) ? 64 : 128;   // A row length (elems)

  const int bnq = tid & 15;      // B: n-quad
  const int bkq = tid >> 4;      // B: k-quad 0..15

  // Gather row indices: 2 row-groups x 7 neighbor slots, per-lane registers.
  int idx[2][7];
  if constexpr (MODE != 0) {
#pragma unroll
    for (int rg = 0; rg < 2; ++rg) {
      int r = mTile + wv * 32 + rg * 16 + r16;
      if (r >= M) r = M - 1;
      const int gb = (r >= NH) ? 1 : 0;
      const int gn = r - gb * NH;
#pragma unroll
      for (int j = 0; j < 7; ++j)
        idx[rg][j] = gb * NH + clampi(neigh[gn * 7 + j], NH);
    }
  }

  f32x4 acc[2][4];
#pragma unroll
  for (int a = 0; a < 2; ++a)
#pragma unroll
    for (int i = 0; i < 4; ++i) acc[a][i] = (f32x4){0.f, 0.f, 0.f, 0.f};

  short8 areg[3][2][2];   // [slot][rowgroup][ks] — statically indexed (unrolled)

  auto loadA = [&](int slot, int ch) {
    if constexpr (MODE == 0) {
#pragma unroll
      for (int rg = 0; rg < 2; ++rg) {
        int r = mTile + wv * 32 + rg * 16 + r16;
        if (r >= M) r = M - 1;
        const ushort_t* base = Asrc + (size_t)r * 128 + ch * 64 + q * 8;
        areg[slot][rg][0] = *(const short8*)(base);
        areg[slot][rg][1] = *(const short8*)(base + 32);
      }
    } else {
      const int j  = (MODE == 1) ? (ch >> 1) : ch;
      const int cb = (MODE == 1) ? ((ch & 1) << 6) : 0;
#pragma unroll
      for (int rg = 0; rg < 2; ++rg) {
        const ushort_t* base = Asrc + (size_t)idx[rg][j] * ROWE + cb + q * 8;
        areg[slot][rg][0] = *(const short8*)(base);
        areg[slot][rg][1] = *(const short8*)(base + 32);
      }
    }
  };

  // W chunk (64k x 64n fp32) -> regs. Thread: 4 k-rows x 4 n, f32x4 each.
  auto loadW = [&](f32x4* f, int ch) {
    const int kk = ch * 64 + bkq * 4;
#pragma unroll
    for (int e = 0; e < 4; ++e)
      f[e] = *(const f32x4*)(Wf + (size_t)(kk + e) * NW + nTile + bnq * 4);
  };
  // Regs -> Bs[buf], bf16, [n][64] rows, 8-slot XOR swizzle.
  auto writeB = [&](int buf, f32x4* f) {
    const int sl = bkq >> 1, hh = bkq & 1;
#pragma unroll
    for (int d = 0; d < 4; ++d) {
      const int n  = bnq * 4 + d;
      const int sp = (sl ^ n) & 7;
      s16x4 v;
      v[0] = (short)f2bf(f[0][d]); v[1] = (short)f2bf(f[1][d]);
      v[2] = (short)f2bf(f[2][d]); v[3] = (short)f2bf(f[3][d]);
      *(s16x4*)&Bs[buf][n * 64 + sp * 8 + hh * 4] = v;
    }
  };

  auto compute = [&](int slot, int buf) {
#pragma unroll
    for (int ks = 0; ks < 2; ++ks) {
      const int sl = ks * 4 + q;
#pragma unroll
      for (int ct = 0; ct < 4; ++ct) {
        const int n  = ct * 16 + r16;
        const int sp = (sl ^ n) & 7;
        const short8 b = *(const short8*)&Bs[buf][n * 64 + sp * 8];
#pragma unroll
        for (int rg = 0; rg < 2; ++rg)
          acc[rg][ct] = __builtin_amdgcn_mfma_f32_16x16x32_bf16(
              areg[slot][rg][ks], b, acc[rg][ct], 0, 0, 0);
      }
    }
  };

  // Prologue: W first (so later waits on W leave A in flight), then A x2.
  {
    f32x4 f[4];
    loadW(f, 0);
    loadA(0, 0);
    if (NCH > 1) loadA(1, 1);
    writeB(0, f);
  }
  lds_barrier();

#pragma unroll
  for (int ch = 0; ch < NCH; ++ch) {
    f32x4 f[4];
    const bool pf = (ch + 1 < NCH);
    if (pf) loadW(f, ch + 1);              // W issued before newest A-gathers
    if (ch + 2 < NCH) loadA((ch + 2) % 3, ch + 2);
    compute(ch % 3, ch & 1);
    if (pf) {
      writeB((ch + 1) & 1, f);             // waits W only (A issued after W)
      lds_barrier();                       // handoff; vmcnt untouched
    }
  }

  // epilogue: C/D layout col=lane&15, row=(lane>>4)*4+reg
  float s1a[4] = {0.f, 0.f, 0.f, 0.f};
  float s2a[4] = {0.f, 0.f, 0.f, 0.f};
#pragma unroll
  for (int ct = 0; ct < 4; ++ct) {
    const int colg = nTile + ct * 16 + r16;
    const float bv = bias[colg];
#pragma unroll
    for (int rg = 0; rg < 2; ++rg) {
#pragma unroll
      for (int i = 0; i < 4; ++i) {
        const int rowg = mTile + wv * 32 + rg * 16 + q * 4 + i;
        const float y = acc[rg][ct][i] + bv;
        if (rowg < M) {
          if constexpr (MODE == 2)
            ((float*)OutV)[(size_t)rowg * NW + colg] = y;
          else
            ((ushort_t*)OutV)[(size_t)rowg * NW + colg] = f2bf(y);
          if constexpr (FSTATS) { s1a[ct] += y; s2a[ct] += y * y; }
        }
      }
    }
  }

  if constexpr (FSTATS) {
    __syncthreads();                     // all LDS use done; reuse as scratch
    float* Sred  = (float*)&Bs[0][0];    // [4 waves][64 ch]
    float* S2red = Sred + 256;
#pragma unroll
    for (int ct = 0; ct < 4; ++ct) {
      float v = s1a[ct], w = s2a[ct];
      v += __shfl_xor(v, 16, 64); v += __shfl_xor(v, 32, 64);
      w += __shfl_xor(w, 16, 64); w += __shfl_xor(w, 32, 64);
      if (q == 0) {
        Sred[wv * 64 + ct * 16 + r16]  = v;
        S2red[wv * 64 + ct * 16 + r16] = w;
      }
    }
    __syncthreads();
    if (tid < 64) {
      float v = Sred[tid] + Sred[64 + tid] + Sred[128 + tid] + Sred[192 + tid];
      float w = S2red[tid] + S2red[64 + tid] + S2red[128 + tid] + S2red[192 + tid];
      float* p = statsPart + (size_t)(blockIdx.y & 15) * 128;
      atomicAdd(&p[tid], v);
      atomicAdd(&p[64 + tid], w);
    }
  }
}

// ---------------------------------------------------------------------------
// xup build: pick/mean from h ((NR,448) bf16 viewed as (NR7,64)), writing the
// LOW 64 channels of xcat rows (row stride 128).
// ---------------------------------------------------------------------------
__global__ __launch_bounds__(256) void build_xup_kernel(
    const ushort_t* __restrict__ h, const int* __restrict__ top,
    const int* __restrict__ down, ushort_t* __restrict__ xcatB, long long total)
{
  const long long gid = (long long)blockIdx.x * 256 + threadIdx.x;
  if (gid >= total) return;
  const int n  = (int)(gid >> 3);
  const int c0 = (int)(gid & 7) * 8;
  short8 v;
  if (n < NR) {
    const int idx = clampi(top[n], NR7);
    v = *(const short8*)(h + (size_t)idx * 64 + c0);
  } else {
    const int d  = n - NR;
    const int i0 = clampi(down[d * 2], NR7);
    const int i1 = clampi(down[d * 2 + 1], NR7);
    short8 u0 = *(const short8*)(h + (size_t)i0 * 64 + c0);
    short8 u1 = *(const short8*)(h + (size_t)i1 * 64 + c0);
#pragma unroll
    for (int i = 0; i < 8; ++i)
      v[i] = (short)f2bf(0.5f * (bf2f((ushort_t)u0[i]) + bf2f((ushort_t)u1[i])));
  }
  *(short8*)(xcatB + (size_t)n * 128 + c0) = v;
}

// x2 fp32 -> bf16 into HIGH 64 channels of xcat (row stride 128)
__global__ __launch_bounds__(256) void cvt_x2_kernel(
    const float* __restrict__ x2, ushort_t* __restrict__ xcat, long long n8)
{
  const long long gid = (long long)blockIdx.x * 256 + threadIdx.x;
  if (gid >= n8) return;
  const long long n = gid >> 3;
  const int c0 = (int)(gid & 7) * 8;
  const f32x4 f0 = *(const f32x4*)(x2 + n * 64 + c0);
  const f32x4 f1 = *(const f32x4*)(x2 + n * 64 + c0 + 4);
  short8 v;
#pragma unroll
  for (int i = 0; i < 4; ++i) {
    v[i]     = (short)f2bf(f0[i]);
    v[i + 4] = (short)f2bf(f1[i]);
  }
  *(short8*)(xcat + n * 128 + 64 + c0) = v;
}

// x1 fp32 -> bf16 dense [40962][128]
__global__ __launch_bounds__(256) void cvt_bf_kernel(
    const float* __restrict__ src, ushort_t* __restrict__ dst, long long n8)
{
  const long long gid = (long long)blockIdx.x * 256 + threadIdx.x;
  if (gid >= n8) return;
  const f32x4 f0 = *(const f32x4*)(src + gid * 8);
  const f32x4 f1 = *(const f32x4*)(src + gid * 8 + 4);
  short8 v;
#pragma unroll
  for (int i = 0; i < 4; ++i) {
    v[i]     = (short)f2bf(f0[i]);
    v[i + 4] = (short)f2bf(f1[i]);
  }
  *(short8*)(dst + gid * 8) = v;
}

__global__ __launch_bounds__(256) void zero_kernel(float* __restrict__ p, int n) {
  const int gid = blockIdx.x * 256 + threadIdx.x;
  if (gid < n) p[gid] = 0.f;
}

// Fallback stats over fp32 buffer -> 16 partial slices
__global__ __launch_bounds__(256) void stats_f32_kernel(
    const float* __restrict__ buf, float* __restrict__ part, int rows)
{
  const int tid = threadIdx.x;
  const int c   = tid & 63;
  const int rl  = tid >> 6;
  float s = 0.f, s2 = 0.f;
  for (int r = blockIdx.x * 4 + rl; r < rows; r += gridDim.x * 4) {
    const float v = buf[(size_t)r * 64 + c];
    s += v; s2 += v * v;
  }
  __shared__ float sh[2][256];
  sh[0][tid] = s; sh[1][tid] = s2;
  __syncthreads();
  if (tid < 64) {
#pragma unroll
    for (int i = 1; i < 4; ++i) { s += sh[0][tid + 64 * i]; s2 += sh[1][tid + 64 * i]; }
    float* p = part + (size_t)(blockIdx.x & 15) * 128;
    atomicAdd(&p[c], s);
    atomicAdd(&p[64 + c], s2);
  }
}

// Fallback stats over bf16 buffer -> 16 partial slices
__global__ __launch_bounds__(256) void stats_bf16_kernel(
    const ushort_t* __restrict__ buf, float* __restrict__ part, int rows)
{
  const int tid = threadIdx.x;
  const int c   = tid & 63;
  const int rl  = tid >> 6;
  float s = 0.f, s2 = 0.f;
  for (int r = blockIdx.x * 4 + rl; r < rows; r += gridDim.x * 4) {
    const float v = bf2f(buf[(size_t)r * 64 + c]);
    s += v; s2 += v * v;
  }
  __shared__ float sh[2][256];
  sh[0][tid] = s; sh[1][tid] = s2;
  __syncthreads();
  if (tid < 64) {
#pragma unroll
    for (int i = 1; i < 4; ++i) { s += sh[0][tid + 64 * i]; s2 += sh[1][tid + 64 * i]; }
    float* p = part + (size_t)(blockIdx.x & 15) * 128;
    atomicAdd(&p[c], s);
    atomicAdd(&p[64 + c], s2);
  }
}

// Reduce 16 partial slices -> final [sc[64] | sh[64]] at part+2048
__global__ void finalize_kernel(float* __restrict__ part,
                                const float* __restrict__ gamma,
                                const float* __restrict__ beta)
{
  const int c = threadIdx.x;  // 64
  float s = 0.f, s2 = 0.f;
  for (int i = 0; i < 16; ++i) { s += part[i * 128 + c]; s2 += part[i * 128 + 64 + c]; }
  const float invN = 1.0f / (float)M_CV;
  const float mean = s * invN;
  float var = fmaxf(s2 * invN - mean * mean, 0.f);
  const float sc = gamma[c] * rsqrtf(var + BN_EPS);
  float* fin = part + 2048;
  fin[c] = sc;
  fin[64 + c] = beta[c] - mean * sc;
}

// In-place y = lrelu(v*sc[c] + sh[c]); fin = [sc[64] | sh[64]]
template<bool F32>
__global__ __launch_bounds__(256) void bnl_kernel(
    void* __restrict__ bufV, const float* __restrict__ fin, long long nvec)
{
  const long long gid = (long long)blockIdx.x * 256 + threadIdx.x;
  if (gid >= nvec) return;
  if constexpr (F32) {
    float* buf = (float*)bufV;
    const int c0 = (int)((gid * 4) & 63);
    f32x4 v = *(f32x4*)(buf + gid * 4);
#pragma unroll
    for (int i = 0; i < 4; ++i) {
      const float y = v[i] * fin[c0 + i] + fin[64 + c0 + i];
      v[i] = (y >= 0.f) ? y : SLOPE * y;
    }
    *(f32x4*)(buf + gid * 4) = v;
  } else {
    ushort_t* buf = (ushort_t*)bufV;
    const int c0 = (int)((gid * 8) & 63);
    short8 v = *(short8*)(buf + gid * 8);
#pragma unroll
    for (int i = 0; i < 8; ++i) {
      float y = bf2f((ushort_t)v[i]) * fin[c0 + i] + fin[64 + c0 + i];
      y = (y >= 0.f) ? y : SLOPE * y;
      v[i] = (short)f2bf(y);
    }
    *(short8*)(buf + gid * 8) = v;
  }
}

// ---------------------------------------------------------------------------
extern "C" void kernel_launch(void* const* d_in, const int* in_sizes, int n_in,
                              void* d_out, int out_size, void* d_ws, size_t ws_size,
                              hipStream_t stream)
{
  const float* x1   = (const float*)d_in[0];
  const float* x2   = (const float*)d_in[1];
  const int*   neigh= (const int*)d_in[2];
  const int*   top  = (const int*)d_in[3];
  const int*   down = (const int*)d_in[4];
  const float* upW  = (const float*)d_in[5];
  const float* upb  = (const float*)d_in[6];
  const float* c1W  = (const float*)d_in[7];
  const float* c1b  = (const float*)d_in[8];
  const float* g1   = (const float*)d_in[9];
  const float* b1   = (const float*)d_in[10];
  const float* c2W  = (const float*)d_in[11];
  const float* c2b  = (const float*)d_in[12];
  const float* g2   = (const float*)d_in[13];
  const float* b2   = (const float*)d_in[14];

  // d_out (83,887,104 B) staging plan:
  //   [0, 83886080)  xcat bf16 [B*NH][128]: cols 0:64 = xup, 64:128 = bf16(x2)
  //   x1bf (10,486,272 B) overlays the start of batch-b's xcat region; dead
  //   before build_xup/cvt_x2 write there (strictly sequential stream).
  //   xcat dead after conv1 -> out fp32 reuses d_out.
  // ws: y1 bf16 [B*NH][64] = 41,943,552 (h bf16 36.7MB overlays it in phase 1).
  //   Gated tail (+17,408 B): st1 (8,704) + st2 (8,704).
  // Weights are read fp32 directly from d_in inside the GEMMs (during conv1
  // the live set xcat+y1 leaves only ~91KB slack -> no room for Wt).
  char* dob = (char*)d_out;
  ushort_t* xcat = (ushort_t*)dob;
  float*    outb = (float*)d_out;
  ushort_t* hbuf = (ushort_t*)d_ws;
  ushort_t* ybuf = (ushort_t*)d_ws;

  const bool gated = ws_size >= (size_t)(41943552 + 17408);
  float* st1 = gated ? (float*)((char*)d_ws + 41943552) : (float*)d_out;
  float* st2 = gated ? (float*)((char*)d_ws + 41943552 + 8704) : (float*)d_ws;

  if (gated) zero_kernel<<<17, 256, 0, stream>>>(st1, 4352);  // st1+st2 adjacent

  // Phase 1 — per batch: x1->bf16 (overlay); h = x1bf @ upW + upb; xup->xcat
  for (int b = 0; b < 2; ++b) {
    ushort_t* x1bf = xcat + (size_t)b * NH * 128;
    cvt_bf_kernel<<<2561, 256, 0, stream>>>(x1 + (size_t)b * M_UP * 128,
                                            x1bf, 655392LL);
    gemm_conv<0, 2, false><<<dim3(7, 321), 256, 0, stream>>>(
        x1bf, nullptr, upW, upb, hbuf, nullptr, M_UP, 448);
    build_xup_kernel<<<5121, 256, 0, stream>>>(
        hbuf, top, down, xcat + (size_t)b * NH * 128, (long long)NH * 8);
  }
  // x2 -> bf16 high channels (after both up-GEMMs: overwrites x1bf overlays)
  cvt_x2_kernel<<<10241, 256, 0, stream>>>(x2, xcat, 2621472LL);

  // Phase 2 — y1 = meshconv1(xcat) -> ws (+ fused BN1 stats if gated)
  if (gated) {
    gemm_conv<1, 14, true><<<dim3(1, 2561), 256, 0, stream>>>(
        xcat, neigh, c1W, c1b, ybuf, st1, M_CV, 64);
  } else {
    gemm_conv<1, 14, false><<<dim3(1, 2561), 256, 0, stream>>>(
        xcat, neigh, c1W, c1b, ybuf, nullptr, M_CV, 64);
    zero_kernel<<<9, 256, 0, stream>>>(st1, 2176);     // xcat dead now
    stats_bf16_kernel<<<2048, 256, 0, stream>>>(ybuf, st1, M_CV);
  }
  finalize_kernel<<<1, 64, 0, stream>>>(st1, g1, b1);
  bnl_kernel<false><<<10241, 256, 0, stream>>>(ybuf, st1 + 2048, 2621472LL);

  // Phase 3 — out = meshconv2(y1) -> d_out fp32 (+ fused BN2 stats if gated)
  if (gated) {
    gemm_conv<2, 7, true><<<dim3(1, 2561), 256, 0, stream>>>(
        ybuf, neigh, c2W, c2b, outb, st2, M_CV, 64);
  } else {
    gemm_conv<2, 7, false><<<dim3(1, 2561), 256, 0, stream>>>(
        ybuf, neigh, c2W, c2b, outb, nullptr, M_CV, 64);
    zero_kernel<<<9, 256, 0, stream>>>(st2, 2176);     // y1 dead now
    stats_f32_kernel<<<2048, 256, 0, stream>>>(outb, st2, M_CV);
  }
  finalize_kernel<<<1, 64, 0, stream>>>(st2, g2, b2);
  bnl_kernel<true><<<20481, 256, 0, stream>>>(outb, st2 + 2048, 5242944LL);
}

// Round 4
// 524.968 us; speedup vs baseline: 1.0629x; 1.0294x over previous
//
#include <hip/hip_runtime.h>
#include <stdint.h>

// Problem constants (B=2, Nr=40962, in_ch=128, out_ch=64). FP32 I/O.
#define NR     40962
#define NH     163842      // 4*NR-6
#define NR7    286734      // NR*7
#define M_UP   40962
#define M_CV   327684      // B*NH
#define BN_EPS 1e-5f
#define SLOPE  0.2f

typedef __attribute__((ext_vector_type(8))) short  short8;
typedef __attribute__((ext_vector_type(4))) float  f32x4;
typedef unsigned short ushort_t;

__device__ __forceinline__ ushort_t f2bf(float f) {
  union { float f; uint32_t u; } v; v.f = f;
  uint32_t r = v.u + 0x7fffu + ((v.u >> 16) & 1u);  // RNE
  return (ushort_t)(r >> 16);
}
__device__ __forceinline__ float bf2f(ushort_t h) {
  union { uint32_t u; float f; } v; v.u = ((uint32_t)h) << 16;
  return v.f;
}
__device__ __forceinline__ int clampi(int v, int hi) {
  v = v < 0 ? 0 : v;
  return v >= hi ? hi - 1 : v;
}

// ---------------------------------------------------------------------------
// Gather-GEMM, 512x64 tile, 16 waves (1024 thr), 32 rows/wave.
// __launch_bounds__(1024) HW-forces VGPR<=128 (16-wave block must co-reside)
// => 4 waves/SIMD, no spill (core regs: acc 32 + areg 32 + idx 14 ~ 100).
// B staged to LDS ONCE per stage (KHALF k-elems, rows padded to KHALF+8 so
// row stride = 912B = 228 dwords = 4 mod 32 -> every ds_read_b128 octet hits
// 8 distinct 16B slots: conflict-free, no swizzle). K-loop is BARRIER-FREE
// within a stage: waves free-run, A gathered global->VGPR (16B/lane, exact
// MFMA fragment), 1-chunk-ahead register double buffer; compiler emits
// per-wave counted vmcnt. Only NSTAGE-1 stage-transition barrier pairs.
// MODE 0: dense A bf16 [M][128], K=128 (up-GEMM), out bf16 stride NW.
// MODE 1: conv1 gather, ch->(j=ch>>1, half=ch&1), row=xcat[idx][128], out bf16.
// MODE 2: conv2 gather, j=ch, row=y1[idx][64], out fp32.
// FSTATS: fused per-channel sum/sumsq -> statsPart[16 slices][128].
// ---------------------------------------------------------------------------
template<int MODE, int KHALF, int NSTAGE, int NCH, bool FSTATS>
__global__ __launch_bounds__(1024) void gemm_conv(
    const ushort_t* __restrict__ Asrc,
    const int*      __restrict__ neigh,
    const float*    __restrict__ Wf,     // fp32 [K][NW]
    const float*    __restrict__ bias,
    void*           __restrict__ OutV,
    float*          __restrict__ statsPart,
    int M, int NW)
{
  constexpr int RS = KHALF + 8;          // padded row stride (elems)
  __shared__ __align__(16) ushort_t Bs[64 * RS];

  const int tid  = threadIdx.x;
  const int wv   = tid >> 6;             // 0..15
  const int lane = tid & 63;
  const int r16  = lane & 15;
  const int q    = lane >> 4;
  const int mTile = blockIdx.y * 512;
  const int nTile = blockIdx.x * 64;
  constexpr int ROWE = (MODE == 2) ? 64 : 128;   // A row length (elems)

  // Gather row indices: 2 row-groups x 7 neighbor slots, per-lane registers.
  int idx[2][7];
  if constexpr (MODE != 0) {
#pragma unroll
    for (int rg = 0; rg < 2; ++rg) {
      int r = mTile + wv * 32 + rg * 16 + r16;
      if (r >= M) r = M - 1;
      const int gb = (r >= NH) ? 1 : 0;
      const int gn = r - gb * NH;
#pragma unroll
      for (int j = 0; j < 7; ++j)
        idx[rg][j] = gb * NH + clampi(neigh[gn * 7 + j], NH);
    }
  }

  f32x4 acc[2][4];
#pragma unroll
  for (int a = 0; a < 2; ++a)
#pragma unroll
    for (int i = 0; i < 4; ++i) acc[a][i] = (f32x4){0.f, 0.f, 0.f, 0.f};

  short8 areg[2][2][2];   // [slot][rowgroup][ks] — statically indexed

  auto loadA = [&](int slot, int ch) {
    if constexpr (MODE == 0) {
#pragma unroll
      for (int rg = 0; rg < 2; ++rg) {
        int r = mTile + wv * 32 + rg * 16 + r16;
        if (r >= M) r = M - 1;
        const ushort_t* base = Asrc + (size_t)r * 128 + ch * 64 + q * 8;
        areg[slot][rg][0] = *(const short8*)(base);
        areg[slot][rg][1] = *(const short8*)(base + 32);
      }
    } else {
      const int j  = (MODE == 1) ? (ch >> 1) : ch;
      const int cb = (MODE == 1) ? ((ch & 1) << 6) : 0;
#pragma unroll
      for (int rg = 0; rg < 2; ++rg) {
        const ushort_t* base = Asrc + (size_t)idx[rg][j] * ROWE + cb + q * 8;
        areg[slot][rg][0] = *(const short8*)(base);
        areg[slot][rg][1] = *(const short8*)(base + 32);
      }
    }
  };

  // Stage B: W fp32 [K][NW] -> Bs[n][RS] bf16. Thread: n = tid&63,
  // 8-elem k-slots strided by 16 across the 16 sub-groups. Coalesced per-k
  // (lanes n=0..63 read 256B rows); write octets hit distinct 16B slots
  // (n*RS*2 = 912B = 4 dwords mod 32 -> conflict-free).
  auto stageB = [&](int s) {
    const int n   = tid & 63;
    const int sub = tid >> 6;            // 0..15
    for (int slot = sub; slot < KHALF / 8; slot += 16) {
      const int kg = s * KHALF + slot * 8;
      float f[8];
#pragma unroll
      for (int u = 0; u < 8; ++u)
        f[u] = Wf[(size_t)(kg + u) * NW + nTile + n];
      short8 v;
#pragma unroll
      for (int u = 0; u < 8; ++u) v[u] = (short)f2bf(f[u]);
      *(short8*)&Bs[n * RS + slot * 8] = v;
    }
  };

  auto compute = [&](int slot, int chLoc) {
#pragma unroll
    for (int ks = 0; ks < 2; ++ks) {
      const int kk = chLoc * 64 + ks * 32 + q * 8;
#pragma unroll
      for (int ct = 0; ct < 4; ++ct) {
        const short8 b = *(const short8*)&Bs[(ct * 16 + r16) * RS + kk];
#pragma unroll
        for (int rg = 0; rg < 2; ++rg)
          acc[rg][ct] = __builtin_amdgcn_mfma_f32_16x16x32_bf16(
              areg[slot][rg][ks], b, acc[rg][ct], 0, 0, 0);
      }
    }
  };

  loadA(0, 0);            // in flight under the whole B-staging
  stageB(0);
  __syncthreads();

#pragma unroll
  for (int s = 0; s < NSTAGE; ++s) {
    if (s > 0) {
      __syncthreads();    // all waves done reading previous stage's Bs
      stageB(s);
      __syncthreads();
    }
#pragma unroll
    for (int chLoc = 0; chLoc < KHALF / 64; ++chLoc) {
      const int ch = s * (KHALF / 64) + chLoc;
      if (ch + 1 < NCH) loadA((ch + 1) & 1, ch + 1);
      compute(ch & 1, chLoc);
    }
  }

  // epilogue: C/D layout col=lane&15, row=(lane>>4)*4+reg
  float s1a[4] = {0.f, 0.f, 0.f, 0.f};
  float s2a[4] = {0.f, 0.f, 0.f, 0.f};
#pragma unroll
  for (int ct = 0; ct < 4; ++ct) {
    const int colg = nTile + ct * 16 + r16;
    const float bv = bias[colg];
#pragma unroll
    for (int rg = 0; rg < 2; ++rg) {
#pragma unroll
      for (int i = 0; i < 4; ++i) {
        const int rowg = mTile + wv * 32 + rg * 16 + q * 4 + i;
        const float y = acc[rg][ct][i] + bv;
        if (rowg < M) {
          if constexpr (MODE == 2)
            ((float*)OutV)[(size_t)rowg * NW + colg] = y;
          else
            ((ushort_t*)OutV)[(size_t)rowg * NW + colg] = f2bf(y);
          if constexpr (FSTATS) { s1a[ct] += y; s2a[ct] += y * y; }
        }
      }
    }
  }

  if constexpr (FSTATS) {
    __syncthreads();                     // all Bs reads done; reuse as scratch
    float* Sred  = (float*)&Bs[0];       // [16 waves][64 ch]
    float* S2red = Sred + 1024;
#pragma unroll
    for (int ct = 0; ct < 4; ++ct) {
      float v = s1a[ct], w = s2a[ct];
      v += __shfl_xor(v, 16, 64); v += __shfl_xor(v, 32, 64);
      w += __shfl_xor(w, 16, 64); w += __shfl_xor(w, 32, 64);
      if (q == 0) {
        Sred[wv * 64 + ct * 16 + r16]  = v;
        S2red[wv * 64 + ct * 16 + r16] = w;
      }
    }
    __syncthreads();
    if (tid < 64) {
      float v = 0.f, w = 0.f;
#pragma unroll
      for (int i = 0; i < 16; ++i) {
        v += Sred[i * 64 + tid];
        w += S2red[i * 64 + tid];
      }
      float* p = statsPart + (size_t)(blockIdx.y & 15) * 128;
      atomicAdd(&p[tid], v);
      atomicAdd(&p[64 + tid], w);
    }
  }
}

// ---------------------------------------------------------------------------
// xup build: pick/mean from h ((NR,448) bf16 viewed as (NR7,64)), writing the
// LOW 64 channels of xcat rows (row stride 128).
// ---------------------------------------------------------------------------
__global__ __launch_bounds__(256) void build_xup_kernel(
    const ushort_t* __restrict__ h, const int* __restrict__ top,
    const int* __restrict__ down, ushort_t* __restrict__ xcatB, long long total)
{
  const long long gid = (long long)blockIdx.x * 256 + threadIdx.x;
  if (gid >= total) return;
  const int n  = (int)(gid >> 3);
  const int c0 = (int)(gid & 7) * 8;
  short8 v;
  if (n < NR) {
    const int idx = clampi(top[n], NR7);
    v = *(const short8*)(h + (size_t)idx * 64 + c0);
  } else {
    const int d  = n - NR;
    const int i0 = clampi(down[d * 2], NR7);
    const int i1 = clampi(down[d * 2 + 1], NR7);
    short8 u0 = *(const short8*)(h + (size_t)i0 * 64 + c0);
    short8 u1 = *(const short8*)(h + (size_t)i1 * 64 + c0);
#pragma unroll
    for (int i = 0; i < 8; ++i)
      v[i] = (short)f2bf(0.5f * (bf2f((ushort_t)u0[i]) + bf2f((ushort_t)u1[i])));
  }
  *(short8*)(xcatB + (size_t)n * 128 + c0) = v;
}

// x2 fp32 -> bf16 into HIGH 64 channels of xcat (row stride 128)
__global__ __launch_bounds__(256) void cvt_x2_kernel(
    const float* __restrict__ x2, ushort_t* __restrict__ xcat, long long n8)
{
  const long long gid = (long long)blockIdx.x * 256 + threadIdx.x;
  if (gid >= n8) return;
  const long long n = gid >> 3;
  const int c0 = (int)(gid & 7) * 8;
  const f32x4 f0 = *(const f32x4*)(x2 + n * 64 + c0);
  const f32x4 f1 = *(const f32x4*)(x2 + n * 64 + c0 + 4);
  short8 v;
#pragma unroll
  for (int i = 0; i < 4; ++i) {
    v[i]     = (short)f2bf(f0[i]);
    v[i + 4] = (short)f2bf(f1[i]);
  }
  *(short8*)(xcat + n * 128 + 64 + c0) = v;
}

// x1 fp32 -> bf16 dense [40962][128]
__global__ __launch_bounds__(256) void cvt_bf_kernel(
    const float* __restrict__ src, ushort_t* __restrict__ dst, long long n8)
{
  const long long gid = (long long)blockIdx.x * 256 + threadIdx.x;
  if (gid >= n8) return;
  const f32x4 f0 = *(const f32x4*)(src + gid * 8);
  const f32x4 f1 = *(const f32x4*)(src + gid * 8 + 4);
  short8 v;
#pragma unroll
  for (int i = 0; i < 4; ++i) {
    v[i]     = (short)f2bf(f0[i]);
    v[i + 4] = (short)f2bf(f1[i]);
  }
  *(short8*)(dst + gid * 8) = v;
}

__global__ __launch_bounds__(256) void zero_kernel(float* __restrict__ p, int n) {
  const int gid = blockIdx.x * 256 + threadIdx.x;
  if (gid < n) p[gid] = 0.f;
}

// Fallback stats over fp32 buffer -> 16 partial slices
__global__ __launch_bounds__(256) void stats_f32_kernel(
    const float* __restrict__ buf, float* __restrict__ part, int rows)
{
  const int tid = threadIdx.x;
  const int c   = tid & 63;
  const int rl  = tid >> 6;
  float s = 0.f, s2 = 0.f;
  for (int r = blockIdx.x * 4 + rl; r < rows; r += gridDim.x * 4) {
    const float v = buf[(size_t)r * 64 + c];
    s += v; s2 += v * v;
  }
  __shared__ float sh[2][256];
  sh[0][tid] = s; sh[1][tid] = s2;
  __syncthreads();
  if (tid < 64) {
#pragma unroll
    for (int i = 1; i < 4; ++i) { s += sh[0][tid + 64 * i]; s2 += sh[1][tid + 64 * i]; }
    float* p = part + (size_t)(blockIdx.x & 15) * 128;
    atomicAdd(&p[c], s);
    atomicAdd(&p[64 + c], s2);
  }
}

// Fallback stats over bf16 buffer -> 16 partial slices
__global__ __launch_bounds__(256) void stats_bf16_kernel(
    const ushort_t* __restrict__ buf, float* __restrict__ part, int rows)
{
  const int tid = threadIdx.x;
  const int c   = tid & 63;
  const int rl  = tid >> 6;
  float s = 0.f, s2 = 0.f;
  for (int r = blockIdx.x * 4 + rl; r < rows; r += gridDim.x * 4) {
    const float v = bf2f(buf[(size_t)r * 64 + c]);
    s += v; s2 += v * v;
  }
  __shared__ float sh[2][256];
  sh[0][tid] = s; sh[1][tid] = s2;
  __syncthreads();
  if (tid < 64) {
#pragma unroll
    for (int i = 1; i < 4; ++i) { s += sh[0][tid + 64 * i]; s2 += sh[1][tid + 64 * i]; }
    float* p = part + (size_t)(blockIdx.x & 15) * 128;
    atomicAdd(&p[c], s);
    atomicAdd(&p[64 + c], s2);
  }
}

// Reduce 16 partial slices -> final [sc[64] | sh[64]] at part+2048
__global__ void finalize_kernel(float* __restrict__ part,
                                const float* __restrict__ gamma,
                                const float* __restrict__ beta)
{
  const int c = threadIdx.x;  // 64
  float s = 0.f, s2 = 0.f;
  for (int i = 0; i < 16; ++i) { s += part[i * 128 + c]; s2 += part[i * 128 + 64 + c]; }
  const float invN = 1.0f / (float)M_CV;
  const float mean = s * invN;
  float var = fmaxf(s2 * invN - mean * mean, 0.f);
  const float sc = gamma[c] * rsqrtf(var + BN_EPS);
  float* fin = part + 2048;
  fin[c] = sc;
  fin[64 + c] = beta[c] - mean * sc;
}

// In-place y = lrelu(v*sc[c] + sh[c]); fin = [sc[64] | sh[64]]
template<bool F32>
__global__ __launch_bounds__(256) void bnl_kernel(
    void* __restrict__ bufV, const float* __restrict__ fin, long long nvec)
{
  const long long gid = (long long)blockIdx.x * 256 + threadIdx.x;
  if (gid >= nvec) return;
  if constexpr (F32) {
    float* buf = (float*)bufV;
    const int c0 = (int)((gid * 4) & 63);
    f32x4 v = *(f32x4*)(buf + gid * 4);
#pragma unroll
    for (int i = 0; i < 4; ++i) {
      const float y = v[i] * fin[c0 + i] + fin[64 + c0 + i];
      v[i] = (y >= 0.f) ? y : SLOPE * y;
    }
    *(f32x4*)(buf + gid * 4) = v;
  } else {
    ushort_t* buf = (ushort_t*)bufV;
    const int c0 = (int)((gid * 8) & 63);
    short8 v = *(short8*)(buf + gid * 8);
#pragma unroll
    for (int i = 0; i < 8; ++i) {
      float y = bf2f((ushort_t)v[i]) * fin[c0 + i] + fin[64 + c0 + i];
      y = (y >= 0.f) ? y : SLOPE * y;
      v[i] = (short)f2bf(y);
    }
    *(short8*)(buf + gid * 8) = v;
  }
}

// ---------------------------------------------------------------------------
extern "C" void kernel_launch(void* const* d_in, const int* in_sizes, int n_in,
                              void* d_out, int out_size, void* d_ws, size_t ws_size,
                              hipStream_t stream)
{
  const float* x1   = (const float*)d_in[0];
  const float* x2   = (const float*)d_in[1];
  const int*   neigh= (const int*)d_in[2];
  const int*   top  = (const int*)d_in[3];
  const int*   down = (const int*)d_in[4];
  const float* upW  = (const float*)d_in[5];
  const float* upb  = (const float*)d_in[6];
  const float* c1W  = (const float*)d_in[7];
  const float* c1b  = (const float*)d_in[8];
  const float* g1   = (const float*)d_in[9];
  const float* b1   = (const float*)d_in[10];
  const float* c2W  = (const float*)d_in[11];
  const float* c2b  = (const float*)d_in[12];
  const float* g2   = (const float*)d_in[13];
  const float* b2   = (const float*)d_in[14];

  // d_out (83,887,104 B) staging plan:
  //   [0, 83886080)  xcat bf16 [B*NH][128]: cols 0:64 = xup, 64:128 = bf16(x2)
  //   x1bf (10,486,272 B) overlays the start of batch-b's xcat region; dead
  //   before build_xup/cvt_x2 write there (strictly sequential stream).
  //   xcat dead after conv1 -> out fp32 reuses d_out.
  // ws: y1 bf16 [B*NH][64] = 41,943,552 (h bf16 36.7MB overlays it in phase 1).
  //   Gated tail (+17,408 B): st1 (8,704) + st2 (8,704).
  // Weights are read fp32 directly from d_in inside the GEMMs (during conv1
  // the live set xcat+y1 leaves only ~91KB slack -> no room for Wt).
  char* dob = (char*)d_out;
  ushort_t* xcat = (ushort_t*)dob;
  float*    outb = (float*)d_out;
  ushort_t* hbuf = (ushort_t*)d_ws;
  ushort_t* ybuf = (ushort_t*)d_ws;

  const bool gated = ws_size >= (size_t)(41943552 + 17408);
  float* st1 = gated ? (float*)((char*)d_ws + 41943552) : (float*)d_out;
  float* st2 = gated ? (float*)((char*)d_ws + 41943552 + 8704) : (float*)d_ws;

  if (gated) zero_kernel<<<17, 256, 0, stream>>>(st1, 4352);  // st1+st2 adjacent

  // Phase 1 — per batch: x1->bf16 (overlay); h = x1bf @ upW + upb; xup->xcat
  for (int b = 0; b < 2; ++b) {
    ushort_t* x1bf = xcat + (size_t)b * NH * 128;
    cvt_bf_kernel<<<2561, 256, 0, stream>>>(x1 + (size_t)b * M_UP * 128,
                                            x1bf, 655392LL);
    gemm_conv<0, 128, 1, 2, false><<<dim3(7, 81), 1024, 0, stream>>>(
        x1bf, nullptr, upW, upb, hbuf, nullptr, M_UP, 448);
    build_xup_kernel<<<5121, 256, 0, stream>>>(
        hbuf, top, down, xcat + (size_t)b * NH * 128, (long long)NH * 8);
  }
  // x2 -> bf16 high channels (after both up-GEMMs: overwrites x1bf overlays)
  cvt_x2_kernel<<<10241, 256, 0, stream>>>(x2, xcat, 2621472LL);

  // Phase 2 — y1 = meshconv1(xcat) -> ws (+ fused BN1 stats if gated)
  if (gated) {
    gemm_conv<1, 448, 2, 14, true><<<dim3(1, 641), 1024, 0, stream>>>(
        xcat, neigh, c1W, c1b, ybuf, st1, M_CV, 64);
  } else {
    gemm_conv<1, 448, 2, 14, false><<<dim3(1, 641), 1024, 0, stream>>>(
        xcat, neigh, c1W, c1b, ybuf, nullptr, M_CV, 64);
    zero_kernel<<<9, 256, 0, stream>>>(st1, 2176);     // xcat dead now
    stats_bf16_kernel<<<2048, 256, 0, stream>>>(ybuf, st1, M_CV);
  }
  finalize_kernel<<<1, 64, 0, stream>>>(st1, g1, b1);
  bnl_kernel<false><<<10241, 256, 0, stream>>>(ybuf, st1 + 2048, 2621472LL);

  // Phase 3 — out = meshconv2(y1) -> d_out fp32 (+ fused BN2 stats if gated)
  if (gated) {
    gemm_conv<2, 448, 1, 7, true><<<dim3(1, 641), 1024, 0, stream>>>(
        ybuf, neigh, c2W, c2b, outb, st2, M_CV, 64);
  } else {
    gemm_conv<2, 448, 1, 7, false><<<dim3(1, 641), 1024, 0, stream>>>(
        ybuf, neigh, c2W, c2b, outb, nullptr, M_CV, 64);
    zero_kernel<<<9, 256, 0, stream>>>(st2, 2176);     // y1 dead now
    stats_f32_kernel<<<2048, 256, 0, stream>>>(outb, st2, M_CV);
  }
  finalize_kernel<<<1, 64, 0, stream>>>(st2, g2, b2);
  bnl_kernel<true><<<20481, 256, 0, stream>>>(outb, st2 + 2048, 5242944LL);
}

// Round 5
// 516.676 us; speedup vs baseline: 1.0799x; 1.0160x over previous
//
#include <hip/hip_runtime.h>
#include <stdint.h>

// Problem constants (B=2, Nr=40962, in_ch=128, out_ch=64). FP32 I/O.
#define NR     40962
#define NH     163842      // 4*NR-6
#define NR7    286734      // NR*7
#define M_UP   40962
#define M_CV   327684      // B*NH
#define BN_EPS 1e-5f
#define SLOPE  0.2f

typedef __attribute__((ext_vector_type(8))) short  short8;
typedef __attribute__((ext_vector_type(4))) float  f32x4;
typedef unsigned short ushort_t;

__device__ __forceinline__ ushort_t f2bf(float f) {
  union { float f; uint32_t u; } v; v.f = f;
  uint32_t r = v.u + 0x7fffu + ((v.u >> 16) & 1u);  // RNE
  return (ushort_t)(r >> 16);
}
__device__ __forceinline__ float bf2f(ushort_t h) {
  union { uint32_t u; float f; } v; v.u = ((uint32_t)h) << 16;
  return v.f;
}
__device__ __forceinline__ int clampi(int v, int hi) {
  v = v < 0 ? 0 : v;
  return v >= hi ? hi - 1 : v;
}

// ---------------------------------------------------------------------------
// Gather-GEMM, 256x64 tile, 8 waves (512 thr), 32 rows/wave.
// __launch_bounds__(512,2): the empirically-calibrated config that yields a
// 128-VGPR budget WITHOUT spill (R2: (256,2)->128 ok; (256,4)->64 spill;
// (1024,none)->56 spill+36MB scratch traffic). Register need ~115.
// A: global->VGPR gather (16B/lane = the exact MFMA fragment), 3-slot ring
//    (2 chunks in flight) — barrier-free K-loop, compiler emits counted
//    per-wave vmcnt waits.
// B: staged to LDS ONCE per stage (KHALF k), rows padded to KHALF+8 elems
//    (912B stride = 4 dwords mod 32 -> ds_read_b128 octets balanced across
//    bank groups). Only stage-transition barriers (2 for conv1, 0 steady).
// MODE 0: dense A bf16 [M][128], K=128 (up-GEMM), out bf16 stride NW.
// MODE 1: conv1 gather, ch->(j=ch>>1, half=ch&1), row=xcat[idx][128], out bf16.
// MODE 2: conv2 gather, j=ch, row=y1[idx][64], out fp32.
// FSTATS: fused per-channel sum/sumsq -> statsPart[16 slices][128].
// ---------------------------------------------------------------------------
template<int MODE, int KHALF, int NSTAGE, int NCH, bool FSTATS>
__global__ __launch_bounds__(512, 2) void gemm_conv(
    const ushort_t* __restrict__ Asrc,
    const int*      __restrict__ neigh,
    const float*    __restrict__ Wf,     // fp32 [K][NW]
    const float*    __restrict__ bias,
    void*           __restrict__ OutV,
    float*          __restrict__ statsPart,
    int M, int NW)
{
  constexpr int RS = KHALF + 8;          // padded row stride (elems)
  __shared__ __align__(16) ushort_t Bs[64 * RS];

  const int tid  = threadIdx.x;
  const int wv   = tid >> 6;             // 0..7
  const int lane = tid & 63;
  const int r16  = lane & 15;
  const int q    = lane >> 4;
  const int mTile = blockIdx.y * 256;
  const int nTile = blockIdx.x * 64;
  constexpr int ROWE = (MODE == 2) ? 64 : 128;   // A row length (elems)

  // Gather row indices: 2 row-groups x 7 neighbor slots, per-lane registers.
  int idx[2][7];
  if constexpr (MODE != 0) {
#pragma unroll
    for (int rg = 0; rg < 2; ++rg) {
      int r = mTile + wv * 32 + rg * 16 + r16;
      if (r >= M) r = M - 1;
      const int gb = (r >= NH) ? 1 : 0;
      const int gn = r - gb * NH;
#pragma unroll
      for (int j = 0; j < 7; ++j)
        idx[rg][j] = gb * NH + clampi(neigh[gn * 7 + j], NH);
    }
  }

  f32x4 acc[2][4];
#pragma unroll
  for (int a = 0; a < 2; ++a)
#pragma unroll
    for (int i = 0; i < 4; ++i) acc[a][i] = (f32x4){0.f, 0.f, 0.f, 0.f};

  short8 areg[3][2][2];   // [ringslot][rowgroup][ks] — statically indexed

  auto loadA = [&](int slot, int ch) {
    if constexpr (MODE == 0) {
#pragma unroll
      for (int rg = 0; rg < 2; ++rg) {
        int r = mTile + wv * 32 + rg * 16 + r16;
        if (r >= M) r = M - 1;
        const ushort_t* base = Asrc + (size_t)r * 128 + ch * 64 + q * 8;
        areg[slot][rg][0] = *(const short8*)(base);
        areg[slot][rg][1] = *(const short8*)(base + 32);
      }
    } else {
      const int j  = (MODE == 1) ? (ch >> 1) : ch;
      const int cb = (MODE == 1) ? ((ch & 1) << 6) : 0;
#pragma unroll
      for (int rg = 0; rg < 2; ++rg) {
        const ushort_t* base = Asrc + (size_t)idx[rg][j] * ROWE + cb + q * 8;
        areg[slot][rg][0] = *(const short8*)(base);
        areg[slot][rg][1] = *(const short8*)(base + 32);
      }
    }
  };

  // Stage B: W fp32 [K][NW] -> Bs[n][RS] bf16. Thread: n = tid&63, covers
  // 8-elem k-slots strided by 8 subgroups. Coalesced per-k (lanes n=0..63
  // read 256B rows); write octets balanced across bank groups (RS pad).
  auto stageB = [&](int s) {
    const int n   = tid & 63;
    const int sub = tid >> 6;            // 0..7
    for (int slot = sub; slot < KHALF / 8; slot += 8) {
      const int kg = s * KHALF + slot * 8;
      float f[8];
#pragma unroll
      for (int u = 0; u < 8; ++u)
        f[u] = Wf[(size_t)(kg + u) * NW + nTile + n];
      short8 v;
#pragma unroll
      for (int u = 0; u < 8; ++u) v[u] = (short)f2bf(f[u]);
      *(short8*)&Bs[n * RS + slot * 8] = v;
    }
  };

  auto compute = [&](int slot, int chLoc) {
#pragma unroll
    for (int ks = 0; ks < 2; ++ks) {
      const int kk = chLoc * 64 + ks * 32 + q * 8;
#pragma unroll
      for (int ct = 0; ct < 4; ++ct) {
        const short8 b = *(const short8*)&Bs[(ct * 16 + r16) * RS + kk];
#pragma unroll
        for (int rg = 0; rg < 2; ++rg)
          acc[rg][ct] = __builtin_amdgcn_mfma_f32_16x16x32_bf16(
              areg[slot][rg][ks], b, acc[rg][ct], 0, 0, 0);
      }
    }
  };

  // Prologue: 2 chunks of A in flight under the whole B-staging.
  loadA(0, 0);
  if constexpr (NCH > 1) loadA(1, 1);
  stageB(0);
  __syncthreads();

#pragma unroll
  for (int s = 0; s < NSTAGE; ++s) {
    if (s > 0) {
      __syncthreads();    // all waves done reading previous stage's Bs
      stageB(s);
      __syncthreads();
    }
#pragma unroll
    for (int chLoc = 0; chLoc < KHALF / 64; ++chLoc) {
      const int ch = s * (KHALF / 64) + chLoc;
      if (ch + 2 < NCH) loadA((ch + 2) % 3, ch + 2);
      compute(ch % 3, chLoc);
    }
  }

  // epilogue: C/D layout col=lane&15, row=(lane>>4)*4+reg
  float s1a[4] = {0.f, 0.f, 0.f, 0.f};
  float s2a[4] = {0.f, 0.f, 0.f, 0.f};
#pragma unroll
  for (int ct = 0; ct < 4; ++ct) {
    const int colg = nTile + ct * 16 + r16;
    const float bv = bias[colg];
#pragma unroll
    for (int rg = 0; rg < 2; ++rg) {
#pragma unroll
      for (int i = 0; i < 4; ++i) {
        const int rowg = mTile + wv * 32 + rg * 16 + q * 4 + i;
        const float y = acc[rg][ct][i] + bv;
        if (rowg < M) {
          if constexpr (MODE == 2)
            ((float*)OutV)[(size_t)rowg * NW + colg] = y;
          else
            ((ushort_t*)OutV)[(size_t)rowg * NW + colg] = f2bf(y);
          if constexpr (FSTATS) { s1a[ct] += y; s2a[ct] += y * y; }
        }
      }
    }
  }

  if constexpr (FSTATS) {
    __syncthreads();                     // all Bs reads done; reuse as scratch
    float* Sred  = (float*)&Bs[0];       // [8 waves][64 ch]
    float* S2red = Sred + 512;
#pragma unroll
    for (int ct = 0; ct < 4; ++ct) {
      float v = s1a[ct], w = s2a[ct];
      v += __shfl_xor(v, 16, 64); v += __shfl_xor(v, 32, 64);
      w += __shfl_xor(w, 16, 64); w += __shfl_xor(w, 32, 64);
      if (q == 0) {
        Sred[wv * 64 + ct * 16 + r16]  = v;
        S2red[wv * 64 + ct * 16 + r16] = w;
      }
    }
    __syncthreads();
    if (tid < 64) {
      float v = 0.f, w = 0.f;
#pragma unroll
      for (int i = 0; i < 8; ++i) {
        v += Sred[i * 64 + tid];
        w += S2red[i * 64 + tid];
      }
      float* p = statsPart + (size_t)(blockIdx.y & 15) * 128;
      atomicAdd(&p[tid], v);
      atomicAdd(&p[64 + tid], w);
    }
  }
}

// ---------------------------------------------------------------------------
// xup build: pick/mean from h ((NR,448) bf16 viewed as (NR7,64)), writing the
// LOW 64 channels of xcat rows (row stride 128).
// ---------------------------------------------------------------------------
__global__ __launch_bounds__(256) void build_xup_kernel(
    const ushort_t* __restrict__ h, const int* __restrict__ top,
    const int* __restrict__ down, ushort_t* __restrict__ xcatB, long long total)
{
  const long long gid = (long long)blockIdx.x * 256 + threadIdx.x;
  if (gid >= total) return;
  const int n  = (int)(gid >> 3);
  const int c0 = (int)(gid & 7) * 8;
  short8 v;
  if (n < NR) {
    const int idx = clampi(top[n], NR7);
    v = *(const short8*)(h + (size_t)idx * 64 + c0);
  } else {
    const int d  = n - NR;
    const int i0 = clampi(down[d * 2], NR7);
    const int i1 = clampi(down[d * 2 + 1], NR7);
    short8 u0 = *(const short8*)(h + (size_t)i0 * 64 + c0);
    short8 u1 = *(const short8*)(h + (size_t)i1 * 64 + c0);
#pragma unroll
    for (int i = 0; i < 8; ++i)
      v[i] = (short)f2bf(0.5f * (bf2f((ushort_t)u0[i]) + bf2f((ushort_t)u1[i])));
  }
  *(short8*)(xcatB + (size_t)n * 128 + c0) = v;
}

// x2 fp32 -> bf16 into HIGH 64 channels of xcat (row stride 128)
__global__ __launch_bounds__(256) void cvt_x2_kernel(
    const float* __restrict__ x2, ushort_t* __restrict__ xcat, long long n8)
{
  const long long gid = (long long)blockIdx.x * 256 + threadIdx.x;
  if (gid >= n8) return;
  const long long n = gid >> 3;
  const int c0 = (int)(gid & 7) * 8;
  const f32x4 f0 = *(const f32x4*)(x2 + n * 64 + c0);
  const f32x4 f1 = *(const f32x4*)(x2 + n * 64 + c0 + 4);
  short8 v;
#pragma unroll
  for (int i = 0; i < 4; ++i) {
    v[i]     = (short)f2bf(f0[i]);
    v[i + 4] = (short)f2bf(f1[i]);
  }
  *(short8*)(xcat + n * 128 + 64 + c0) = v;
}

// x1 fp32 -> bf16 dense [40962][128]
__global__ __launch_bounds__(256) void cvt_bf_kernel(
    const float* __restrict__ src, ushort_t* __restrict__ dst, long long n8)
{
  const long long gid = (long long)blockIdx.x * 256 + threadIdx.x;
  if (gid >= n8) return;
  const f32x4 f0 = *(const f32x4*)(src + gid * 8);
  const f32x4 f1 = *(const f32x4*)(src + gid * 8 + 4);
  short8 v;
#pragma unroll
  for (int i = 0; i < 4; ++i) {
    v[i]     = (short)f2bf(f0[i]);
    v[i + 4] = (short)f2bf(f1[i]);
  }
  *(short8*)(dst + gid * 8) = v;
}

__global__ __launch_bounds__(256) void zero_kernel(float* __restrict__ p, int n) {
  const int gid = blockIdx.x * 256 + threadIdx.x;
  if (gid < n) p[gid] = 0.f;
}

// Fallback stats over fp32 buffer -> 16 partial slices
__global__ __launch_bounds__(256) void stats_f32_kernel(
    const float* __restrict__ buf, float* __restrict__ part, int rows)
{
  const int tid = threadIdx.x;
  const int c   = tid & 63;
  const int rl  = tid >> 6;
  float s = 0.f, s2 = 0.f;
  for (int r = blockIdx.x * 4 + rl; r < rows; r += gridDim.x * 4) {
    const float v = buf[(size_t)r * 64 + c];
    s += v; s2 += v * v;
  }
  __shared__ float sh[2][256];
  sh[0][tid] = s; sh[1][tid] = s2;
  __syncthreads();
  if (tid < 64) {
#pragma unroll
    for (int i = 1; i < 4; ++i) { s += sh[0][tid + 64 * i]; s2 += sh[1][tid + 64 * i]; }
    float* p = part + (size_t)(blockIdx.x & 15) * 128;
    atomicAdd(&p[c], s);
    atomicAdd(&p[64 + c], s2);
  }
}

// Fallback stats over bf16 buffer -> 16 partial slices
__global__ __launch_bounds__(256) void stats_bf16_kernel(
    const ushort_t* __restrict__ buf, float* __restrict__ part, int rows)
{
  const int tid = threadIdx.x;
  const int c   = tid & 63;
  const int rl  = tid >> 6;
  float s = 0.f, s2 = 0.f;
  for (int r = blockIdx.x * 4 + rl; r < rows; r += gridDim.x * 4) {
    const float v = bf2f(buf[(size_t)r * 64 + c]);
    s += v; s2 += v * v;
  }
  __shared__ float sh[2][256];
  sh[0][tid] = s; sh[1][tid] = s2;
  __syncthreads();
  if (tid < 64) {
#pragma unroll
    for (int i = 1; i < 4; ++i) { s += sh[0][tid + 64 * i]; s2 += sh[1][tid + 64 * i]; }
    float* p = part + (size_t)(blockIdx.x & 15) * 128;
    atomicAdd(&p[c], s);
    atomicAdd(&p[64 + c], s2);
  }
}

// Reduce 16 partial slices -> final [sc[64] | sh[64]] at part+2048
__global__ void finalize_kernel(float* __restrict__ part,
                                const float* __restrict__ gamma,
                                const float* __restrict__ beta)
{
  const int c = threadIdx.x;  // 64
  float s = 0.f, s2 = 0.f;
  for (int i = 0; i < 16; ++i) { s += part[i * 128 + c]; s2 += part[i * 128 + 64 + c]; }
  const float invN = 1.0f / (float)M_CV;
  const float mean = s * invN;
  float var = fmaxf(s2 * invN - mean * mean, 0.f);
  const float sc = gamma[c] * rsqrtf(var + BN_EPS);
  float* fin = part + 2048;
  fin[c] = sc;
  fin[64 + c] = beta[c] - mean * sc;
}

// In-place y = lrelu(v*sc[c] + sh[c]); fin = [sc[64] | sh[64]]
template<bool F32>
__global__ __launch_bounds__(256) void bnl_kernel(
    void* __restrict__ bufV, const float* __restrict__ fin, long long nvec)
{
  const long long gid = (long long)blockIdx.x * 256 + threadIdx.x;
  if (gid >= nvec) return;
  if constexpr (F32) {
    float* buf = (float*)bufV;
    const int c0 = (int)((gid * 4) & 63);
    f32x4 v = *(f32x4*)(buf + gid * 4);
#pragma unroll
    for (int i = 0; i < 4; ++i) {
      const float y = v[i] * fin[c0 + i] + fin[64 + c0 + i];
      v[i] = (y >= 0.f) ? y : SLOPE * y;
    }
    *(f32x4*)(buf + gid * 4) = v;
  } else {
    ushort_t* buf = (ushort_t*)bufV;
    const int c0 = (int)((gid * 8) & 63);
    short8 v = *(short8*)(buf + gid * 8);
#pragma unroll
    for (int i = 0; i < 8; ++i) {
      float y = bf2f((ushort_t)v[i]) * fin[c0 + i] + fin[64 + c0 + i];
      y = (y >= 0.f) ? y : SLOPE * y;
      v[i] = (short)f2bf(y);
    }
    *(short8*)(buf + gid * 8) = v;
  }
}

// ---------------------------------------------------------------------------
extern "C" void kernel_launch(void* const* d_in, const int* in_sizes, int n_in,
                              void* d_out, int out_size, void* d_ws, size_t ws_size,
                              hipStream_t stream)
{
  const float* x1   = (const float*)d_in[0];
  const float* x2   = (const float*)d_in[1];
  const int*   neigh= (const int*)d_in[2];
  const int*   top  = (const int*)d_in[3];
  const int*   down = (const int*)d_in[4];
  const float* upW  = (const float*)d_in[5];
  const float* upb  = (const float*)d_in[6];
  const float* c1W  = (const float*)d_in[7];
  const float* c1b  = (const float*)d_in[8];
  const float* g1   = (const float*)d_in[9];
  const float* b1   = (const float*)d_in[10];
  const float* c2W  = (const float*)d_in[11];
  const float* c2b  = (const float*)d_in[12];
  const float* g2   = (const float*)d_in[13];
  const float* b2   = (const float*)d_in[14];

  // d_out (83,887,104 B) staging plan:
  //   [0, 83886080)  xcat bf16 [B*NH][128]: cols 0:64 = xup, 64:128 = bf16(x2)
  //   x1bf (10,486,272 B) overlays the start of batch-b's xcat region; dead
  //   before build_xup/cvt_x2 write there (strictly sequential stream).
  //   xcat dead after conv1 -> out fp32 reuses d_out.
  // ws: y1 bf16 [B*NH][64] = 41,943,552 (h bf16 36.7MB overlays it in phase 1).
  //   Gated tail (+17,408 B): st1 (8,704) + st2 (8,704).
  // Weights are read fp32 directly from d_in inside the GEMMs (during conv1
  // the live set xcat+y1 leaves only ~91KB slack -> no room for Wt).
  char* dob = (char*)d_out;
  ushort_t* xcat = (ushort_t*)dob;
  float*    outb = (float*)d_out;
  ushort_t* hbuf = (ushort_t*)d_ws;
  ushort_t* ybuf = (ushort_t*)d_ws;

  const bool gated = ws_size >= (size_t)(41943552 + 17408);
  float* st1 = gated ? (float*)((char*)d_ws + 41943552) : (float*)d_out;
  float* st2 = gated ? (float*)((char*)d_ws + 41943552 + 8704) : (float*)d_ws;

  if (gated) zero_kernel<<<17, 256, 0, stream>>>(st1, 4352);  // st1+st2 adjacent

  // Phase 1 — per batch: x1->bf16 (overlay); h = x1bf @ upW + upb; xup->xcat
  for (int b = 0; b < 2; ++b) {
    ushort_t* x1bf = xcat + (size_t)b * NH * 128;
    cvt_bf_kernel<<<2561, 256, 0, stream>>>(x1 + (size_t)b * M_UP * 128,
                                            x1bf, 655392LL);
    gemm_conv<0, 128, 1, 2, false><<<dim3(7, 161), 512, 0, stream>>>(
        x1bf, nullptr, upW, upb, hbuf, nullptr, M_UP, 448);
    build_xup_kernel<<<5121, 256, 0, stream>>>(
        hbuf, top, down, xcat + (size_t)b * NH * 128, (long long)NH * 8);
  }
  // x2 -> bf16 high channels (after both up-GEMMs: overwrites x1bf overlays)
  cvt_x2_kernel<<<10241, 256, 0, stream>>>(x2, xcat, 2621472LL);

  // Phase 2 — y1 = meshconv1(xcat) -> ws (+ fused BN1 stats if gated)
  if (gated) {
    gemm_conv<1, 448, 2, 14, true><<<dim3(1, 1281), 512, 0, stream>>>(
        xcat, neigh, c1W, c1b, ybuf, st1, M_CV, 64);
  } else {
    gemm_conv<1, 448, 2, 14, false><<<dim3(1, 1281), 512, 0, stream>>>(
        xcat, neigh, c1W, c1b, ybuf, nullptr, M_CV, 64);
    zero_kernel<<<9, 256, 0, stream>>>(st1, 2176);     // xcat dead now
    stats_bf16_kernel<<<2048, 256, 0, stream>>>(ybuf, st1, M_CV);
  }
  finalize_kernel<<<1, 64, 0, stream>>>(st1, g1, b1);
  bnl_kernel<false><<<10241, 256, 0, stream>>>(ybuf, st1 + 2048, 2621472LL);

  // Phase 3 — out = meshconv2(y1) -> d_out fp32 (+ fused BN2 stats if gated)
  if (gated) {
    gemm_conv<2, 448, 1, 7, true><<<dim3(1, 1281), 512, 0, stream>>>(
        ybuf, neigh, c2W, c2b, outb, st2, M_CV, 64);
  } else {
    gemm_conv<2, 448, 1, 7, false><<<dim3(1, 1281), 512, 0, stream>>>(
        ybuf, neigh, c2W, c2b, outb, nullptr, M_CV, 64);
    zero_kernel<<<9, 256, 0, stream>>>(st2, 2176);     // y1 dead now
    stats_f32_kernel<<<2048, 256, 0, stream>>>(outb, st2, M_CV);
  }
  finalize_kernel<<<1, 64, 0, stream>>>(st2, g2, b2);
  bnl_kernel<true><<<20481, 256, 0, stream>>>(outb, st2 + 2048, 5242944LL);
}